// Round 2
// 689.385 us; speedup vs baseline: 1.4211x; 1.4211x over previous
//
#include <hip/hip_runtime.h>
#include <math.h>

constexpr int BATCH  = 65536;
constexpr int IN_DIM = 512;
constexpr int LATENT = 32;
constexpr int NTRIL  = 528;        // 32*33/2
constexpr float BN_EPS = 1e-5f;
constexpr float SLOPE  = 0.01f;

constexpr int RPB  = 64;           // batch rows per block (both kernels)
constexpr int SUBR = 8;            // rows per cov sub-batch
constexpr int HSTR = 36;           // h_sh stride (16B aligned, breaks pow2)
constexpr int LSTR = 36;           // stride of one L-row
constexpr int LROW = LATENT * LSTR;
constexpr int PSTR = 36;           // enc partial-sum stride

__device__ __forceinline__ float leaky(float v) {
    return v >= 0.0f ? v : SLOPE * v;
}

// ================= Kernel A: h = leaky(BN(x @ W_enc + b_enc)) =================
// 4 waves split K (128 each). lane = batch row -> per-lane-unique streaming x
// loads. W_enc addresses are wave-uniform (readfirstlane) -> scalar s_loads,
// so the inner loop is pure v_fmac with an SGPR operand. LDS reduce across
// the 4 K-partials, then BN epilogue.
extern "C" __global__ __launch_bounds__(256, 4)
void enc_kernel(const float* __restrict__ x,
                const float* __restrict__ W_enc,
                const float* __restrict__ b_enc,
                const float* __restrict__ bn_gamma,
                const float* __restrict__ bn_beta,
                const float* __restrict__ bn_mean,
                const float* __restrict__ bn_var,
                float* __restrict__ h_out)
{
    __shared__ float part[4][RPB][PSTR];   // 36864 B

    const int t = threadIdx.x;
    const int w = __builtin_amdgcn_readfirstlane(t >> 6);  // wave id = K-quarter
    const int l = t & 63;                                  // lane = row in block
    const int row0 = blockIdx.x * RPB;

    {
        const float4* __restrict__ xp =
            (const float4*)(x + (size_t)(row0 + l) * IN_DIM + w * (IN_DIM / 4));
        const float* __restrict__ Wq = W_enc + (w * (IN_DIM / 4)) * LATENT;

        float acc[LATENT];
        #pragma unroll
        for (int c = 0; c < LATENT; ++c) acc[c] = 0.0f;

        // 2-deep x prefetch queue; W comes from the scalar pipe.
        float4 q0 = xp[0];
        float4 q1 = xp[1];
        #pragma unroll 2
        for (int k4 = 0; k4 < IN_DIM / 16; ++k4) {   // 32 iters, 4 K each
            const float4 xv = q0;
            q0 = q1;
            // always-in-bounds prefetch: tail re-reads the final element
            const int pf = (k4 < IN_DIM / 16 - 2) ? (k4 + 2) : (IN_DIM / 16 - 1);
            q1 = xp[pf];

            const float* __restrict__ Wk = Wq + (4 * k4) * LATENT;  // uniform
            #pragma unroll
            for (int c = 0; c < LATENT; ++c) acc[c] = fmaf(xv.x, Wk[c],            acc[c]);
            #pragma unroll
            for (int c = 0; c < LATENT; ++c) acc[c] = fmaf(xv.y, Wk[LATENT + c],   acc[c]);
            #pragma unroll
            for (int c = 0; c < LATENT; ++c) acc[c] = fmaf(xv.z, Wk[2*LATENT + c], acc[c]);
            #pragma unroll
            for (int c = 0; c < LATENT; ++c) acc[c] = fmaf(xv.w, Wk[3*LATENT + c], acc[c]);
        }

        #pragma unroll
        for (int c4 = 0; c4 < LATENT / 4; ++c4)
            *(float4*)&part[w][l][4 * c4] =
                make_float4(acc[4*c4+0], acc[4*c4+1], acc[4*c4+2], acc[4*c4+3]);
    }
    __syncthreads();

    {
        const int r  = t >> 2;          // 0..63
        const int c0 = (t & 3) * 8;     // 0,8,16,24
        float v[8];
        #pragma unroll
        for (int i = 0; i < 8; ++i) v[i] = 0.0f;
        #pragma unroll
        for (int ww = 0; ww < 4; ++ww) {
            const float4 p0 = *(const float4*)&part[ww][r][c0];
            const float4 p1 = *(const float4*)&part[ww][r][c0 + 4];
            v[0]+=p0.x; v[1]+=p0.y; v[2]+=p0.z; v[3]+=p0.w;
            v[4]+=p1.x; v[5]+=p1.y; v[6]+=p1.z; v[7]+=p1.w;
        }
        float hv[8];
        #pragma unroll
        for (int i = 0; i < 8; ++i) {
            const int c = c0 + i;
            float u = v[i] + b_enc[c];
            u = bn_gamma[c] * (u - bn_mean[c]) * rsqrtf(bn_var[c] + BN_EPS) + bn_beta[c];
            hv[i] = leaky(u);
        }
        float4* __restrict__ hp = (float4*)(h_out + (size_t)(row0 + r) * LATENT + c0);
        hp[0] = make_float4(hv[0], hv[1], hv[2], hv[3]);
        hp[1] = make_float4(hv[4], hv[5], hv[6], hv[7]);
    }
}

// ================= Kernel B: mus + elts -> L -> cov =================
extern "C" __global__ __launch_bounds__(256)
void dec_kernel(const float* __restrict__ h_in,
                const float* __restrict__ W_mu,
                const float* __restrict__ b_mu,
                const float* __restrict__ W_ch,
                const float* __restrict__ b_ch,
                float* __restrict__ mu_out,
                float* __restrict__ cov_out)
{
    __shared__ float h_sh[RPB][HSTR];      // 9216 B
    __shared__ float L_sh[SUBR][LROW];     // 36864 B (total 46080 B)

    const int t = threadIdx.x;
    const int row0 = blockIdx.x * RPB;

    // ---- load h tile (coalesced) ----
    {
        const int r  = t >> 2;
        const int c0 = (t & 3) * 8;
        const float4* __restrict__ hg =
            (const float4*)(h_in + (size_t)(row0 + r) * LATENT + c0);
        const float4 a0 = hg[0];
        const float4 a1 = hg[1];
        *(float4*)&h_sh[r][c0]     = a0;
        *(float4*)&h_sh[r][c0 + 4] = a1;
    }
    __syncthreads();

    // ---- mus = leaky(h @ W_mu + b_mu) ----
    {
        const int c = t & 31;
        const int g = t >> 5;
        float wmu[LATENT];
        #pragma unroll
        for (int k = 0; k < LATENT; ++k) wmu[k] = W_mu[k * LATENT + c];
        const float bm = b_mu[c];
        #pragma unroll
        for (int j = 0; j < 8; ++j) {
            const int r = g * 8 + j;
            const float4* __restrict__ hr = (const float4*)&h_sh[r][0];
            float a = bm;
            #pragma unroll
            for (int k4 = 0; k4 < 8; ++k4) {
                const float4 hvv = hr[k4];
                a += hvv.x*wmu[4*k4+0] + hvv.y*wmu[4*k4+1]
                   + hvv.z*wmu[4*k4+2] + hvv.w*wmu[4*k4+3];
            }
            mu_out[(size_t)(row0 + r) * LATENT + c] = leaky(a);
        }
    }
    // h_sh read-only from here; L_sh untouched so far -> no barrier needed.

    #pragma unroll 1
    for (int sb = 0; sb < RPB / SUBR; ++sb) {
        const int rbl = sb * SUBR;

        // ---- 3a: elts = leaky(h @ W_ch + b_ch); diag softplus-clip; into L_sh
        // job = (pair of 2 tril elems) x (half of the 8 rows); 528 jobs / 256 thr
        // -> worst thread 3 jobs (1.45x ideal).
        #pragma unroll 1
        for (int jid = t; jid < 2 * (NTRIL / 2); jid += 256) {
            const int q  = jid % (NTRIL / 2);   // 0..263
            const int rh = jid / (NTRIL / 2);   // 0..1 -> rows rh*4..rh*4+3
            const int j0 = 2 * q;

            float2 a[4];
            a[0] = make_float2(b_ch[j0], b_ch[j0 + 1]);
            a[1] = a[0]; a[2] = a[0]; a[3] = a[0];

            const float* __restrict__ wbase = W_ch + j0;
            #pragma unroll
            for (int kq = 0; kq < 8; ++kq) {
                float2 wv[4];
                #pragma unroll
                for (int e = 0; e < 4; ++e)
                    wv[e] = *(const float2*)(wbase + (4*kq + e) * NTRIL);
                #pragma unroll
                for (int rr = 0; rr < 4; ++rr) {
                    const float4 hvv = *(const float4*)&h_sh[rbl + rh*4 + rr][4*kq];
                    a[rr].x += hvv.x*wv[0].x + hvv.y*wv[1].x + hvv.z*wv[2].x + hvv.w*wv[3].x;
                    a[rr].y += hvv.x*wv[0].y + hvv.y*wv[1].y + hvv.z*wv[2].y + hvv.w*wv[3].y;
                }
            }

            #pragma unroll
            for (int e = 0; e < 2; ++e) {
                const int j = j0 + e;
                int ri = (int)((sqrtf(8.0f * (float)j + 1.0f) - 1.0f) * 0.5f);
                if ((ri + 1) * (ri + 2) / 2 <= j) ++ri;
                if (ri * (ri + 1) / 2 > j) --ri;
                const int ci = j - ri * (ri + 1) / 2;
                const bool isdiag = (ci == ri);
                #pragma unroll
                for (int rr = 0; rr < 4; ++rr) {
                    float vv = (e == 0) ? a[rr].x : a[rr].y;
                    vv = leaky(vv);
                    if (isdiag) {
                        float sp = vv > 20.0f ? vv : log1pf(__expf(vv));
                        vv = fminf(fmaxf(sp, 0.001f), 100.0f) + 0.01f;
                    }
                    L_sh[rh*4 + rr][ri * LSTR + ci] = vv;
                }
            }
        }
        __syncthreads();

        // ---- 3b: cov[i][k] = sum_{j<=min(i,k)} L[i][j]*L[k][j] (+0.01 diag)
        {
            const int lr = t >> 5;    // batch row of sub-batch
            const int i  = t & 31;    // cov output row
            const float* __restrict__ Lrow = &L_sh[lr][0];

            float Li[LATENT];
            #pragma unroll
            for (int j = 0; j < LATENT; ++j) {
                const float v = Lrow[i * LSTR + j];
                Li[j] = (j <= i) ? v : 0.0f;
            }

            float cr[LATENT];
            #pragma unroll
            for (int k = 0; k < LATENT; ++k) {
                float a = 0.0f;
                const float* __restrict__ Lk = Lrow + k * LSTR;
                #pragma unroll
                for (int qq = 0; 4 * qq <= k; ++qq) {
                    const float4 wv = *(const float4*)(Lk + 4 * qq);  // broadcast
                    if (4*qq + 0 <= k) a += Li[4*qq+0] * wv.x;
                    if (4*qq + 1 <= k) a += Li[4*qq+1] * wv.y;
                    if (4*qq + 2 <= k) a += Li[4*qq+2] * wv.z;
                    if (4*qq + 3 <= k) a += Li[4*qq+3] * wv.w;
                }
                cr[k] = (k == i) ? a + 0.01f : a;
            }

            const size_t grow = (size_t)(row0 + rbl + lr);
            float4* __restrict__ cp =
                (float4*)(cov_out + grow * (size_t)(LATENT * LATENT) + (size_t)i * LATENT);
            #pragma unroll
            for (int k4 = 0; k4 < 8; ++k4)
                cp[k4] = make_float4(cr[4*k4+0], cr[4*k4+1], cr[4*k4+2], cr[4*k4+3]);
        }
        __syncthreads();
    }
}

extern "C" void kernel_launch(void* const* d_in, const int* in_sizes, int n_in,
                              void* d_out, int out_size, void* d_ws, size_t ws_size,
                              hipStream_t stream) {
    const float* x        = (const float*)d_in[0];
    const float* W_enc    = (const float*)d_in[1];
    const float* b_enc    = (const float*)d_in[2];
    const float* bn_gamma = (const float*)d_in[3];
    const float* bn_beta  = (const float*)d_in[4];
    const float* bn_mean  = (const float*)d_in[5];
    const float* bn_var   = (const float*)d_in[6];
    const float* W_mu     = (const float*)d_in[7];
    const float* b_mu     = (const float*)d_in[8];
    const float* W_ch     = (const float*)d_in[9];
    const float* b_ch     = (const float*)d_in[10];
    float* out = (float*)d_out;

    float* h_out   = out;
    float* mu_out  = out + (size_t)BATCH * LATENT;
    float* cov_out = out + (size_t)2 * BATCH * LATENT;

    enc_kernel<<<dim3(BATCH / RPB), dim3(256), 0, stream>>>(
        x, W_enc, b_enc, bn_gamma, bn_beta, bn_mean, bn_var, h_out);
    dec_kernel<<<dim3(BATCH / RPB), dim3(256), 0, stream>>>(
        h_out, W_mu, b_mu, W_ch, b_ch, mu_out, cov_out);
}

// Round 3
// 672.006 us; speedup vs baseline: 1.4579x; 1.0259x over previous
//
#include <hip/hip_runtime.h>
#include <math.h>

constexpr int BATCH  = 65536;
constexpr int IN_DIM = 512;
constexpr int LATENT = 32;
constexpr int NTRIL  = 528;        // 32*33/2
constexpr float BN_EPS = 1e-5f;
constexpr float SLOPE  = 0.01f;

constexpr int RPB  = 64;           // batch rows per block (both kernels)
constexpr int SUBR = 16;           // rows per cov sub-batch
constexpr int HSTR = 36;           // h_sh stride (16B aligned, breaks pow2)
constexpr int PSTR = 36;           // enc partial-sum stride

// packed-aligned tril layout: row i starts at rstart(i), length 4*ceil((i+1)/4)
// total 576 floats; batch-row stride 584 (=8 mod 32 banks -> lr bank skew)
constexpr int LSTRIDE = 584;

__device__ __host__ __forceinline__ constexpr int rstart(int i) {
    const int g = i >> 2, r = i & 3;
    return 4 * (i + 2 * g * (g - 1) + r * g);
}

__device__ __forceinline__ float leaky(float v) {
    return v >= 0.0f ? v : SLOPE * v;
}

// ================= Kernel A: h = leaky(BN(x @ W_enc + b_enc)) =================
extern "C" __global__ __launch_bounds__(256, 4)
void enc_kernel(const float* __restrict__ x,
                const float* __restrict__ W_enc,
                const float* __restrict__ b_enc,
                const float* __restrict__ bn_gamma,
                const float* __restrict__ bn_beta,
                const float* __restrict__ bn_mean,
                const float* __restrict__ bn_var,
                float* __restrict__ h_out)
{
    __shared__ float part[4][RPB][PSTR];   // 36864 B

    const int t = threadIdx.x;
    const int w = __builtin_amdgcn_readfirstlane(t >> 6);  // wave id = K-quarter
    const int l = t & 63;                                  // lane = row in block
    const int row0 = blockIdx.x * RPB;

    {
        const float4* __restrict__ xp =
            (const float4*)(x + (size_t)(row0 + l) * IN_DIM + w * (IN_DIM / 4));
        const float* __restrict__ Wq = W_enc + (w * (IN_DIM / 4)) * LATENT;

        float acc[LATENT];
        #pragma unroll
        for (int c = 0; c < LATENT; ++c) acc[c] = 0.0f;

        float4 q0 = xp[0];
        float4 q1 = xp[1];
        #pragma unroll 2
        for (int k4 = 0; k4 < IN_DIM / 16; ++k4) {   // 32 iters, 4 K each
            const float4 xv = q0;
            q0 = q1;
            const int pf = (k4 < IN_DIM / 16 - 2) ? (k4 + 2) : (IN_DIM / 16 - 1);
            q1 = xp[pf];

            const float* __restrict__ Wk = Wq + (4 * k4) * LATENT;  // uniform
            #pragma unroll
            for (int c = 0; c < LATENT; ++c) acc[c] = fmaf(xv.x, Wk[c],            acc[c]);
            #pragma unroll
            for (int c = 0; c < LATENT; ++c) acc[c] = fmaf(xv.y, Wk[LATENT + c],   acc[c]);
            #pragma unroll
            for (int c = 0; c < LATENT; ++c) acc[c] = fmaf(xv.z, Wk[2*LATENT + c], acc[c]);
            #pragma unroll
            for (int c = 0; c < LATENT; ++c) acc[c] = fmaf(xv.w, Wk[3*LATENT + c], acc[c]);
        }

        #pragma unroll
        for (int c4 = 0; c4 < LATENT / 4; ++c4)
            *(float4*)&part[w][l][4 * c4] =
                make_float4(acc[4*c4+0], acc[4*c4+1], acc[4*c4+2], acc[4*c4+3]);
    }
    __syncthreads();

    {
        const int r  = t >> 2;          // 0..63
        const int c0 = (t & 3) * 8;     // 0,8,16,24
        float v[8];
        #pragma unroll
        for (int i = 0; i < 8; ++i) v[i] = 0.0f;
        #pragma unroll
        for (int ww = 0; ww < 4; ++ww) {
            const float4 p0 = *(const float4*)&part[ww][r][c0];
            const float4 p1 = *(const float4*)&part[ww][r][c0 + 4];
            v[0]+=p0.x; v[1]+=p0.y; v[2]+=p0.z; v[3]+=p0.w;
            v[4]+=p1.x; v[5]+=p1.y; v[6]+=p1.z; v[7]+=p1.w;
        }
        float hv[8];
        #pragma unroll
        for (int i = 0; i < 8; ++i) {
            const int c = c0 + i;
            float u = v[i] + b_enc[c];
            u = bn_gamma[c] * (u - bn_mean[c]) * rsqrtf(bn_var[c] + BN_EPS) + bn_beta[c];
            hv[i] = leaky(u);
        }
        float4* __restrict__ hp = (float4*)(h_out + (size_t)(row0 + r) * LATENT + c0);
        hp[0] = make_float4(hv[0], hv[1], hv[2], hv[3]);
        hp[1] = make_float4(hv[4], hv[5], hv[6], hv[7]);
    }
}

// ================= Kernel B: mus + elts -> L -> cov =================
extern "C" __global__ __launch_bounds__(256)
void dec_kernel(const float* __restrict__ h_in,
                const float* __restrict__ W_mu,
                const float* __restrict__ b_mu,
                const float* __restrict__ W_ch,
                const float* __restrict__ b_ch,
                float* __restrict__ mu_out,
                float* __restrict__ cov_out)
{
    __shared__ float h_sh[RPB][HSTR];          // 9216 B
    __shared__ float L_sh[SUBR * LSTRIDE];     // 37376 B  (total 46592 B)

    const int t = threadIdx.x;
    const int row0 = blockIdx.x * RPB;

    // ---- zero L_sh once (pads must be exact 0 for full-quad dots) ----
    {
        float4* z4 = (float4*)L_sh;
        const float4 z = make_float4(0.f, 0.f, 0.f, 0.f);
        #pragma unroll 1
        for (int s = t; s < SUBR * LSTRIDE / 4; s += 256) z4[s] = z;
    }

    // ---- load h tile (coalesced) ----
    {
        const int r  = t >> 2;
        const int c0 = (t & 3) * 8;
        const float4* __restrict__ hg =
            (const float4*)(h_in + (size_t)(row0 + r) * LATENT + c0);
        const float4 a0 = hg[0];
        const float4 a1 = hg[1];
        *(float4*)&h_sh[r][c0]     = a0;
        *(float4*)&h_sh[r][c0 + 4] = a1;
    }
    __syncthreads();

    // ---- mus = leaky(h @ W_mu + b_mu) ----
    {
        const int c = t & 31;
        const int g = t >> 5;
        float wmu[LATENT];
        #pragma unroll
        for (int k = 0; k < LATENT; ++k) wmu[k] = W_mu[k * LATENT + c];
        const float bm = b_mu[c];
        #pragma unroll
        for (int j = 0; j < 8; ++j) {
            const int r = g * 8 + j;
            const float4* __restrict__ hr = (const float4*)&h_sh[r][0];
            float a = bm;
            #pragma unroll
            for (int k4 = 0; k4 < 8; ++k4) {
                const float4 hvv = hr[k4];
                a += hvv.x*wmu[4*k4+0] + hvv.y*wmu[4*k4+1]
                   + hvv.z*wmu[4*k4+2] + hvv.w*wmu[4*k4+3];
            }
            mu_out[(size_t)(row0 + r) * LATENT + c] = leaky(a);
        }
    }
    // h_sh read-only from here. L_sh valid slots written in 3a; pads stay 0.

    #pragma unroll 1
    for (int sb = 0; sb < RPB / SUBR; ++sb) {     // 4 sub-batches of 16 rows
        const int rbl = sb * SUBR;

        // ---- 3a: elts = leaky(h @ W_ch + b_ch); diag softplus-clip -> L_sh
        // job = (quad of 4 tril elems) x (pair of rows); 132*8 = 1056 jobs
        #pragma unroll 1
        for (int jid = t; jid < 132 * 8; jid += 256) {
            const int q  = jid % 132;          // elem quad
            const int rg = jid / 132;          // 0..7 -> rows rg*2, rg*2+1
            const int j0 = 4 * q;
            const int r0s = rbl + rg * 2;

            float4 a0 = make_float4(b_ch[j0+0], b_ch[j0+1], b_ch[j0+2], b_ch[j0+3]);
            float4 a1 = a0;

            const float* __restrict__ wbase = W_ch + j0;
            #pragma unroll
            for (int kq = 0; kq < 8; ++kq) {
                const float4 w0 = *(const float4*)(wbase + (4*kq + 0) * NTRIL);
                const float4 w1 = *(const float4*)(wbase + (4*kq + 1) * NTRIL);
                const float4 w2 = *(const float4*)(wbase + (4*kq + 2) * NTRIL);
                const float4 w3 = *(const float4*)(wbase + (4*kq + 3) * NTRIL);
                const float4 h0 = *(const float4*)&h_sh[r0s    ][4*kq];
                const float4 h1 = *(const float4*)&h_sh[r0s + 1][4*kq];
                a0.x += h0.x*w0.x + h0.y*w1.x + h0.z*w2.x + h0.w*w3.x;
                a0.y += h0.x*w0.y + h0.y*w1.y + h0.z*w2.y + h0.w*w3.y;
                a0.z += h0.x*w0.z + h0.y*w1.z + h0.z*w2.z + h0.w*w3.z;
                a0.w += h0.x*w0.w + h0.y*w1.w + h0.z*w2.w + h0.w*w3.w;
                a1.x += h1.x*w0.x + h1.y*w1.x + h1.z*w2.x + h1.w*w3.x;
                a1.y += h1.x*w0.y + h1.y*w1.y + h1.z*w2.y + h1.w*w3.y;
                a1.z += h1.x*w0.z + h1.y*w1.z + h1.z*w2.z + h1.w*w3.z;
                a1.w += h1.x*w0.w + h1.y*w1.w + h1.z*w2.w + h1.w*w3.w;
            }

            #pragma unroll
            for (int e = 0; e < 4; ++e) {
                const int j = j0 + e;
                int ri = (int)((sqrtf(8.0f * (float)j + 1.0f) - 1.0f) * 0.5f);
                if ((ri + 1) * (ri + 2) / 2 <= j) ++ri;
                if (ri * (ri + 1) / 2 > j) --ri;
                const int ci = j - ri * (ri + 1) / 2;
                const bool isdiag = (ci == ri);
                const int off = rstart(ri) + ci;

                float v0 = (e == 0) ? a0.x : (e == 1) ? a0.y : (e == 2) ? a0.z : a0.w;
                float v1 = (e == 0) ? a1.x : (e == 1) ? a1.y : (e == 2) ? a1.z : a1.w;
                v0 = leaky(v0);
                v1 = leaky(v1);
                if (isdiag) {
                    float s0 = v0 > 20.0f ? v0 : log1pf(__expf(v0));
                    float s1 = v1 > 20.0f ? v1 : log1pf(__expf(v1));
                    v0 = fminf(fmaxf(s0, 0.001f), 100.0f) + 0.01f;
                    v1 = fminf(fmaxf(s1, 0.001f), 100.0f) + 0.01f;
                }
                L_sh[(r0s - rbl) * LSTRIDE + off]       = v0;
                L_sh[(r0s - rbl + 1) * LSTRIDE + off]   = v1;
            }
        }
        __syncthreads();

        // ---- 3b: cov rows p and p+16 per thread; Lk stream shared by both
        {
            const int lr = t >> 4;          // 0..15: batch row of sub-batch
            const int p  = t & 15;          // cov rows p, p+16
            const float* __restrict__ Lb = L_sh + lr * LSTRIDE;

            // Li0 = row p (16 floats, zeroed beyond p)
            float a0[16];
            {
                const int s0 = rstart(p);
                #pragma unroll
                for (int qq = 0; qq < 4; ++qq) {
                    const float4 v = *(const float4*)(Lb + s0 + 4*qq);
                    a0[4*qq+0] = (4*qq+0 <= p) ? v.x : 0.0f;
                    a0[4*qq+1] = (4*qq+1 <= p) ? v.y : 0.0f;
                    a0[4*qq+2] = (4*qq+2 <= p) ? v.z : 0.0f;
                    a0[4*qq+3] = (4*qq+3 <= p) ? v.w : 0.0f;
                }
            }
            // Li1 = row p+16 (32 floats, zeroed beyond p+16)
            float a1[32];
            {
                const int i1 = p + 16;
                const int s1 = rstart(i1);
                #pragma unroll
                for (int qq = 0; qq < 8; ++qq) {
                    const float4 v = *(const float4*)(Lb + s1 + 4*qq);
                    a1[4*qq+0] = (4*qq+0 <= i1) ? v.x : 0.0f;
                    a1[4*qq+1] = (4*qq+1 <= i1) ? v.y : 0.0f;
                    a1[4*qq+2] = (4*qq+2 <= i1) ? v.z : 0.0f;
                    a1[4*qq+3] = (4*qq+3 <= i1) ? v.w : 0.0f;
                }
            }

            const size_t grow = (size_t)(row0 + rbl + lr);
            float* __restrict__ cov0 =
                cov_out + grow * (size_t)(LATENT * LATENT) + (size_t)p * LATENT;
            float* __restrict__ cov1 = cov0 + 16 * LATENT;

            float c0[4], c1[4];
            #pragma unroll
            for (int k = 0; k < LATENT; ++k) {
                const int qk = (k >> 2) + 1;            // quads in row k
                const float* __restrict__ Lk = Lb + rstart(k);
                float d0 = 0.0f, d1 = 0.0f;
                #pragma unroll
                for (int qq = 0; qq < qk; ++qq) {
                    const float4 w = *(const float4*)(Lk + 4*qq);
                    if (qq < 4) {
                        d0 += a0[4*qq+0]*w.x + a0[4*qq+1]*w.y
                            + a0[4*qq+2]*w.z + a0[4*qq+3]*w.w;
                    }
                    d1 += a1[4*qq+0]*w.x + a1[4*qq+1]*w.y
                        + a1[4*qq+2]*w.z + a1[4*qq+3]*w.w;
                }
                d0 = (k == p)      ? d0 + 0.01f : d0;
                d1 = (k == p + 16) ? d1 + 0.01f : d1;
                c0[k & 3] = d0;
                c1[k & 3] = d1;
                if ((k & 3) == 3) {
                    *(float4*)(cov0 + (k - 3)) = make_float4(c0[0], c0[1], c0[2], c0[3]);
                    *(float4*)(cov1 + (k - 3)) = make_float4(c1[0], c1[1], c1[2], c1[3]);
                }
            }
        }
        __syncthreads();
    }
}

extern "C" void kernel_launch(void* const* d_in, const int* in_sizes, int n_in,
                              void* d_out, int out_size, void* d_ws, size_t ws_size,
                              hipStream_t stream) {
    const float* x        = (const float*)d_in[0];
    const float* W_enc    = (const float*)d_in[1];
    const float* b_enc    = (const float*)d_in[2];
    const float* bn_gamma = (const float*)d_in[3];
    const float* bn_beta  = (const float*)d_in[4];
    const float* bn_mean  = (const float*)d_in[5];
    const float* bn_var   = (const float*)d_in[6];
    const float* W_mu     = (const float*)d_in[7];
    const float* b_mu     = (const float*)d_in[8];
    const float* W_ch     = (const float*)d_in[9];
    const float* b_ch     = (const float*)d_in[10];
    float* out = (float*)d_out;

    float* h_out   = out;
    float* mu_out  = out + (size_t)BATCH * LATENT;
    float* cov_out = out + (size_t)2 * BATCH * LATENT;

    enc_kernel<<<dim3(BATCH / RPB), dim3(256), 0, stream>>>(
        x, W_enc, b_enc, bn_gamma, bn_beta, bn_mean, bn_var, h_out);
    dec_kernel<<<dim3(BATCH / RPB), dim3(256), 0, stream>>>(
        h_out, W_mu, b_mu, W_ch, b_ch, mu_out, cov_out);
}